// Round 6
// baseline (451.017 us; speedup 1.0000x reference)
//
#include <hip/hip_runtime.h>
#include <hip/hip_cooperative_groups.h>
#include <cstdint>

#define MDIM 2048
#define KDIM 1024
#define CDIM 8192
#define BM 256
#define BN 256
#define BK 32
#define NT (KDIM / BK)      // 32 K-tiles
#define NCHUNK (CDIM / 64)  // 128 chunks of 64 cols

typedef __attribute__((ext_vector_type(8))) __bf16 bf16x8;
typedef __attribute__((ext_vector_type(4))) float f32x4;

// ---------- helpers ----------
__device__ __forceinline__ unsigned short f2bf(float f) {
  unsigned u = __float_as_uint(f);
  u += 0x7fffu + ((u >> 16) & 1u);   // RNE
  return (unsigned short)(u >> 16);
}

__device__ __forceinline__ void async_ld16(const void* g, void* l) {
  __builtin_amdgcn_global_load_lds(
      (__attribute__((address_space(1))) void*)(g),
      (__attribute__((address_space(3))) void*)(l),
      16, 0, 0);
}

// ================= fused mega-kernel (cooperative, 256 blocks x 512 thr) ===========
// phase1 convert | sync | phase2 gemm (R1-verbatim schedule) | sync | phase3 combine
// | sync | phase4 finalize (block 0). 1 block/CU (128KB LDS) -> co-residency exact.
__global__ __launch_bounds__(512, 2) void fused_all(
    const float* __restrict__ x, const int* __restrict__ y,
    const float* __restrict__ cent,
    unsigned short* __restrict__ xb, unsigned short* __restrict__ cb,
    float* __restrict__ c2,
    float* __restrict__ pm, float* __restrict__ pl, int* __restrict__ pidx,
    float* __restrict__ loss_part, float* __restrict__ corr_part,
    float* __restrict__ out) {
  __shared__ __align__(16) char lds[4 * 32768];   // 128 KB, reused by every phase
  cooperative_groups::grid_group grid = cooperative_groups::this_grid();
  const int tid = threadIdx.x;
  const int bid = blockIdx.x;   // 0..255

  // ---------------- phase 1: convert x & cent to bf16; c2 = ||c||^2 ----------------
  {
    const int rt = tid & 255;       // float4 index within row (256 * 16B = 4KB row)
    const int half = tid >> 8;      // 0/1: two rows processed per step
    float* red = (float*)lds;       // [2][4] per-wave partials
    for (int s = 0; s < 20; ++s) {  // 256 blocks * 40 rows = 10240 rows
      const int row = bid * 40 + s * 2 + half;
      const bool isc = row >= MDIM;
      if (!isc) {
        const float4 v = ((const float4*)(x + (size_t)row * KDIM))[rt];
        ushort4 o;
        o.x = f2bf(v.x); o.y = f2bf(v.y); o.z = f2bf(v.z); o.w = f2bf(v.w);
        ((ushort4*)(xb + (size_t)row * KDIM))[rt] = o;
      } else {
        const int r = row - MDIM;
        const float4 v = ((const float4*)(cent + (size_t)r * KDIM))[rt];
        ushort4 o;
        o.x = f2bf(v.x); o.y = f2bf(v.y); o.z = f2bf(v.z); o.w = f2bf(v.w);
        ((ushort4*)(cb + (size_t)r * KDIM))[rt] = o;
        float p = v.x * v.x + v.y * v.y + v.z * v.z + v.w * v.w;
        for (int d = 32; d; d >>= 1) p += __shfl_down(p, d, 64);
        if ((rt & 63) == 0) red[half * 4 + (rt >> 6)] = p;
      }
      __syncthreads();
      if (isc && rt == 0) {
        const int r = row - MDIM;
        c2[r] = red[half * 4 + 0] + red[half * 4 + 1] + red[half * 4 + 2] + red[half * 4 + 3];
      }
      __syncthreads();
    }
  }
  __threadfence();
  grid.sync();
  __threadfence();

  // ---------------- phase 2: gemm_reduce (exact R1 schedule) ----------------
  {
    const int wave = tid >> 6, lane = tid & 63;
    const int wm = wave >> 2, wn = wave & 3;        // 2 x 4 wave grid
    const int quad = lane >> 4, c16 = lane & 15;

    // XCD-chunked block remap (bijective, 256%8==0)
    const int id = bid;
    const int lid = (id & 7) * 32 + (id >> 3);
    const int bm = lid >> 5, bn = lid & 31;
    const int bmBase = bm * BM, bnBase = bn * BN;

    // staging: thread stages 2 A-chunks + 2 B-chunks (16B each) per tile.
    // LDS chunk i holds logical chunk (row=i>>2, c ^ s(row)), s(row)=(row>>1)&3;
    // LDS dest linear (rule #21), swizzle applied to global source + read addr.
    const int r1 = tid >> 2, c1 = (tid & 3) ^ ((r1 >> 1) & 3);
    const int r2 = (tid + 512) >> 2, c2s = (tid & 3) ^ ((r2 >> 1) & 3);
    const char* Ag1 = (const char*)(xb + (size_t)(bmBase + r1) * KDIM + c1 * 8);
    const char* Ag2 = (const char*)(xb + (size_t)(bmBase + r2) * KDIM + c2s * 8);
    const char* Bg1 = (const char*)(cb + (size_t)(bnBase + r1) * KDIM + c1 * 8);
    const char* Bg2 = (const char*)(cb + (size_t)(bnBase + r2) * KDIM + c2s * 8);
    const int wbyte = wave * 1024;

    int aoff[8], boff[4];
#pragma unroll
    for (int mt = 0; mt < 8; ++mt) {
      const int row = wm * 128 + mt * 16 + c16;
      aoff[mt] = row * 64 + ((quad ^ ((row >> 1) & 3)) * 16);
    }
#pragma unroll
    for (int nt = 0; nt < 4; ++nt) {
      const int col = wn * 64 + nt * 16 + c16;
      boff[nt] = col * 64 + ((quad ^ ((col >> 1) & 3)) * 16);
    }

    f32x4 acc[8][4] = {};

#define STAGE(T)                                          \
    {                                                     \
      const int _ko = (T) * (BK * 2);                     \
      char* _sb = &lds[((T) & 3) * 32768];                \
      async_ld16(Ag1 + _ko, _sb + wbyte);                 \
      async_ld16(Ag2 + _ko, _sb + 8192 + wbyte);          \
      async_ld16(Bg1 + _ko, _sb + 16384 + wbyte);         \
      async_ld16(Bg2 + _ko, _sb + 24576 + wbyte);         \
    }

    STAGE(0); STAGE(1); STAGE(2);

#pragma unroll 1
    for (int t = 0; t < NT; ++t) {
      if (t < NT - 2)       asm volatile("s_waitcnt vmcnt(8)" ::: "memory");
      else if (t == NT - 2) asm volatile("s_waitcnt vmcnt(4)" ::: "memory");
      else                  asm volatile("s_waitcnt vmcnt(0)" ::: "memory");
      __builtin_amdgcn_s_barrier();
      __builtin_amdgcn_sched_barrier(0);

      const char* sb = &lds[(t & 3) * 32768];
      bf16x8 a[8], b[4];
#pragma unroll
      for (int mt = 0; mt < 8; ++mt) a[mt] = *(const bf16x8*)(sb + aoff[mt]);
#pragma unroll
      for (int nt = 0; nt < 4; ++nt) b[nt] = *(const bf16x8*)(sb + 16384 + boff[nt]);

      if (t < NT - 3) STAGE(t + 3);

      asm volatile("s_waitcnt lgkmcnt(0)" ::: "memory");
      __builtin_amdgcn_sched_barrier(0);
      __builtin_amdgcn_s_setprio(1);
#pragma unroll
      for (int mt = 0; mt < 8; ++mt)
#pragma unroll
        for (int nt = 0; nt < 4; ++nt)
          acc[mt][nt] = __builtin_amdgcn_mfma_f32_16x16x32_bf16(a[mt], b[nt], acc[mt][nt], 0, 0, 0);
      __builtin_amdgcn_s_setprio(0);
    }
#undef STAGE

    // epilogue: C/D layout col=lane&15, row=quad*4+reg (verified)
    const int colbase = bnBase + wn * 64;
    float c2v[4];
#pragma unroll
    for (int nt = 0; nt < 4; ++nt) c2v[nt] = c2[colbase + nt * 16 + c16];

    const int chunk = bn * 4 + wn;
#pragma unroll
    for (int mt = 0; mt < 8; ++mt) {
#pragma unroll
      for (int r = 0; r < 4; ++r) {
        float sv[4];
#pragma unroll
        for (int nt = 0; nt < 4; ++nt) sv[nt] = 2.0f * acc[mt][nt][r] - c2v[nt];
        float m = sv[0];
        int idx = colbase + c16;
#pragma unroll
        for (int nt = 1; nt < 4; ++nt) {
          if (sv[nt] > m) { m = sv[nt]; idx = colbase + nt * 16 + c16; }
        }
        float l = 0.f;
#pragma unroll
        for (int nt = 0; nt < 4; ++nt) l += __expf(sv[nt] - m);
        for (int d = 1; d < 16; d <<= 1) {
          float om = __shfl_xor(m, d, 64);
          float ol = __shfl_xor(l, d, 64);
          int oi = __shfl_xor(idx, d, 64);
          float M = fmaxf(m, om);
          l = l * __expf(m - M) + ol * __expf(om - M);
          idx = (om > m || (om == m && oi < idx)) ? oi : idx;
          m = M;
        }
        if (c16 == 0) {
          const int row = bmBase + wm * 128 + mt * 16 + quad * 4 + r;
          pm[(size_t)row * NCHUNK + chunk] = m;
          pl[(size_t)row * NCHUNK + chunk] = l;
          pidx[(size_t)row * NCHUNK + chunk] = idx;
        }
      }
    }
  }
  __threadfence();
  grid.sync();
  __threadfence();

  // ---------------- phase 3: per-row combine (4 rows in parallel, 2 iters) ----------------
  {
    const int grp = tid >> 7;        // 0..3 (128-thread group per row)
    const int t = tid & 127;         // chunk id
    float* smA = (float*)lds;        // [4][2] m
    float* slA = smA + 8;            // l
    float* sdA = slA + 8;            // dot
    int*   siA = (int*)(sdA + 8);    // idx
    for (int it = 0; it < 2; ++it) {
      const int row = bid * 8 + it * 4 + grp;   // 256*8 = 2048 rows
      const int yc = y[row];

      float m = pm[(size_t)row * NCHUNK + t];
      float l = pl[(size_t)row * NCHUNK + t];
      int idx = pidx[(size_t)row * NCHUNK + t];

      const float4* xa = (const float4*)(x + (size_t)row * KDIM) + t * 2;
      const float4* ca = (const float4*)(cent + (size_t)yc * KDIM) + t * 2;
      const float4 a0 = xa[0], a1 = xa[1], b0 = ca[0], b1 = ca[1];
      float dot = a0.x * b0.x + a0.y * b0.y + a0.z * b0.z + a0.w * b0.w
                + a1.x * b1.x + a1.y * b1.y + a1.z * b1.z + a1.w * b1.w;

      for (int d = 1; d < 64; d <<= 1) {
        const float om = __shfl_xor(m, d, 64);
        const float ol = __shfl_xor(l, d, 64);
        const int oi = __shfl_xor(idx, d, 64);
        const float od = __shfl_xor(dot, d, 64);
        const float M = fmaxf(m, om);
        l = l * __expf(m - M) + ol * __expf(om - M);
        idx = (om > m || (om == m && oi < idx)) ? oi : idx;
        m = M;
        dot += od;
      }
      const int wv = t >> 6;
      if ((t & 63) == 0) {
        smA[grp * 2 + wv] = m; slA[grp * 2 + wv] = l;
        siA[grp * 2 + wv] = idx; sdA[grp * 2 + wv] = dot;
      }
      __syncthreads();
      if (t == 0) {
        const float m0 = smA[grp * 2], m1 = smA[grp * 2 + 1];
        const float M = fmaxf(m0, m1);
        const float L = slA[grp * 2] * __expf(m0 - M) + slA[grp * 2 + 1] * __expf(m1 - M);
        int g;
        if (m1 > m0 || (m1 == m0 && siA[grp * 2 + 1] < siA[grp * 2])) g = siA[grp * 2 + 1];
        else g = siA[grp * 2];
        const float sy = 2.0f * (sdA[grp * 2] + sdA[grp * 2 + 1]) - c2[yc];
        loss_part[row] = __logf(L) + M - sy;
        corr_part[row] = (g == yc) ? 1.f : 0.f;
      }
      __syncthreads();
    }
  }
  __threadfence();
  grid.sync();
  __threadfence();

  // ---------------- phase 4: finalize (block 0) ----------------
  if (bid == 0) {
    float s0 = 0.f, s1 = 0.f;
    for (int i = tid; i < MDIM; i += 512) { s0 += loss_part[i]; s1 += corr_part[i]; }
    for (int d = 32; d; d >>= 1) {
      s0 += __shfl_down(s0, d, 64);
      s1 += __shfl_down(s1, d, 64);
    }
    float* r0 = (float*)lds;
    float* r1 = r0 + 8;
    if ((tid & 63) == 0) { r0[tid >> 6] = s0; r1[tid >> 6] = s1; }
    __syncthreads();
    if (tid == 0) {
      float a = 0.f, b = 0.f;
#pragma unroll
      for (int w = 0; w < 8; ++w) { a += r0[w]; b += r1[w]; }
      out[0] = a * (1.0f / MDIM);
      out[1] = b * (1.0f / MDIM);
    }
  }
}

// ---------- launch ----------
extern "C" void kernel_launch(void* const* d_in, const int* in_sizes, int n_in,
                              void* d_out, int out_size, void* d_ws, size_t ws_size,
                              hipStream_t stream) {
  const float* x = (const float*)d_in[0];
  const int* y = (const int*)d_in[1];
  const float* cent = (const float*)d_in[2];
  float* out = (float*)d_out;

  char* ws = (char*)d_ws;
  const size_t OFF_XB = 0;                                   // 4 MB
  const size_t OFF_CB = OFF_XB + (size_t)MDIM * KDIM * 2;    // 16 MB
  const size_t OFF_C2 = OFF_CB + (size_t)CDIM * KDIM * 2;    // 32 KB
  const size_t OFF_PM = OFF_C2 + (size_t)CDIM * 4;           // 1 MB
  const size_t OFF_PL = OFF_PM + (size_t)NCHUNK * MDIM * 4;  // 1 MB
  const size_t OFF_PI = OFF_PL + (size_t)NCHUNK * MDIM * 4;  // 1 MB
  const size_t OFF_LP = OFF_PI + (size_t)NCHUNK * MDIM * 4;  // 8 KB
  const size_t OFF_CP = OFF_LP + (size_t)MDIM * 4;           // 8 KB
  const size_t NEED = OFF_CP + (size_t)MDIM * 4;
  if (ws_size < NEED) return;

  unsigned short* xb = (unsigned short*)(ws + OFF_XB);
  unsigned short* cb = (unsigned short*)(ws + OFF_CB);
  float* c2 = (float*)(ws + OFF_C2);
  float* pm = (float*)(ws + OFF_PM);
  float* pl = (float*)(ws + OFF_PL);
  int* pidx = (int*)(ws + OFF_PI);
  float* loss_part = (float*)(ws + OFF_LP);
  float* corr_part = (float*)(ws + OFF_CP);

  void* args[12];
  args[0] = (void*)&x;
  args[1] = (void*)&y;
  args[2] = (void*)&cent;
  args[3] = (void*)&xb;
  args[4] = (void*)&cb;
  args[5] = (void*)&c2;
  args[6] = (void*)&pm;
  args[7] = (void*)&pl;
  args[8] = (void*)&pidx;
  args[9] = (void*)&loss_part;
  args[10] = (void*)&corr_part;
  args[11] = (void*)&out;

  hipLaunchCooperativeKernel(fused_all, dim3(256), dim3(512), args, 0, stream);
}

// Round 7
// 138.003 us; speedup vs baseline: 3.2682x; 3.2682x over previous
//
#include <hip/hip_runtime.h>
#include <cstdint>

#define MDIM 2048
#define KDIM 1024
#define CDIM 8192
#define BM 256
#define BN 256
#define BK 32
#define NT (KDIM / BK)      // 32 K-tiles
#define NCHUNK (CDIM / 64)  // 128 chunks of 64 cols
#define CVT_BLOCKS 1280     // grid-stride over 5120 row-pairs, 4 iters

typedef __attribute__((ext_vector_type(8))) __bf16 bf16x8;
typedef __attribute__((ext_vector_type(4))) float f32x4;
typedef __attribute__((ext_vector_type(8))) unsigned short ushort8;

// ---------- helpers ----------
__device__ __forceinline__ unsigned short f2bf(float f) {
  unsigned u = __float_as_uint(f);
  u += 0x7fffu + ((u >> 16) & 1u);   // RNE
  return (unsigned short)(u >> 16);
}

__device__ __forceinline__ void async_ld16(const void* g, void* l) {
  __builtin_amdgcn_global_load_lds(
      (__attribute__((address_space(1))) void*)(g),
      (__attribute__((address_space(3))) void*)(l),
      16, 0, 0);
}

// ---------- K0: convert x & centroids to bf16 (16B stores); c2 = ||c||^2 ----------
// 256 thr = 4 waves; waves 0,1 -> row 2p (halves 0,1), waves 2,3 -> row 2p+1.
// Each lane: 8 elems = 2 float4 loads + 1 ushort8 (16B) store.
__global__ __launch_bounds__(256) void convert_all(const float* __restrict__ x,
                                                   const float* __restrict__ cent,
                                                   unsigned short* __restrict__ xb,
                                                   unsigned short* __restrict__ cb,
                                                   float* __restrict__ c2) {
  const int t = threadIdx.x;
  const int wv = t >> 6, lane = t & 63;
  const int rsel = wv >> 1;        // which row of the pair
  const int half = wv & 1;         // which half of the row
  const int eidx = half * 64 + lane;   // ushort8 index within row (0..127)
  __shared__ float red[4];
  for (int p = blockIdx.x; p < (MDIM + CDIM) / 2; p += CVT_BLOCKS) {
    const int row = p * 2 + rsel;
    const bool isc = row >= MDIM;
    const float* srcrow = isc ? (cent + (size_t)(row - MDIM) * KDIM)
                              : (x + (size_t)row * KDIM);
    const float4* src = (const float4*)srcrow + eidx * 2;
    const float4 v0 = src[0], v1 = src[1];
    ushort8 o;
    o[0] = f2bf(v0.x); o[1] = f2bf(v0.y); o[2] = f2bf(v0.z); o[3] = f2bf(v0.w);
    o[4] = f2bf(v1.x); o[5] = f2bf(v1.y); o[6] = f2bf(v1.z); o[7] = f2bf(v1.w);
    if (!isc) {
      ((ushort8*)(xb + (size_t)row * KDIM))[eidx] = o;
    } else {
      ((ushort8*)(cb + (size_t)(row - MDIM) * KDIM))[eidx] = o;
      float pq = v0.x * v0.x + v0.y * v0.y + v0.z * v0.z + v0.w * v0.w
               + v1.x * v1.x + v1.y * v1.y + v1.z * v1.z + v1.w * v1.w;
      for (int d = 32; d; d >>= 1) pq += __shfl_down(pq, d, 64);
      if (lane == 0) red[wv] = pq;
    }
    __syncthreads();
    if (isc && half == 0 && lane == 0)
      c2[row - MDIM] = red[wv] + red[wv + 1];
    __syncthreads();   // red[] reused next iteration
  }
}

// ---------- K1: 256x256-tile bf16 MFMA GEMM, 4-slot LDS ring, counted vmcnt ----------
// (exact R1 kernel — best verified: 48.2 us burst, 0 bank conflicts, 68 MB fetch)
// s = 2*x.c - c2, fused per-64col online softmax/argmax epilogue.
// 8 waves (2M x 4N), per-wave output 128x64. LDS ring: 4 slots x (A 16KB + B 16KB).
__global__ __launch_bounds__(512, 2) void gemm_reduce(
    const unsigned short* __restrict__ Ab, const unsigned short* __restrict__ Bb,
    const float* __restrict__ c2,
    float* __restrict__ pm, float* __restrict__ pl, int* __restrict__ pidx) {
  __shared__ __align__(16) char lds[4 * 32768];   // 128 KB

  const int tid = threadIdx.x;
  const int wave = tid >> 6, lane = tid & 63;
  const int wm = wave >> 2, wn = wave & 3;        // 2 x 4 wave grid
  const int quad = lane >> 4, c16 = lane & 15;

  // XCD-chunked block remap: XCD k owns bm=k (A-panel 512KB -> L2-resident)
  const int id = blockIdx.y * gridDim.x + blockIdx.x;      // 0..255
  const int lid = (id & 7) * 32 + (id >> 3);               // bijective, 256%8==0
  const int bm = lid >> 5, bn = lid & 31;
  const int bmBase = bm * BM, bnBase = bn * BN;

  // ---- staging addresses: thread stages 2 A-chunks + 2 B-chunks (16B each) per tile ----
  // LDS chunk i (i = tid, tid+512) holds logical chunk (row = i>>2, c ^ s(row)),
  // s(row) = (row>>1)&3  -> conflict-free swizzle; LDS dest stays linear (rule #21).
  const int r1 = tid >> 2, c1 = (tid & 3) ^ ((r1 >> 1) & 3);
  const int r2 = (tid + 512) >> 2, c2s = (tid & 3) ^ ((r2 >> 1) & 3);
  const char* Ag1 = (const char*)(Ab + (size_t)(bmBase + r1) * KDIM + c1 * 8);
  const char* Ag2 = (const char*)(Ab + (size_t)(bmBase + r2) * KDIM + c2s * 8);
  const char* Bg1 = (const char*)(Bb + (size_t)(bnBase + r1) * KDIM + c1 * 8);
  const char* Bg2 = (const char*)(Bb + (size_t)(bnBase + r2) * KDIM + c2s * 8);
  const int wbyte = wave * 1024;                  // wave-uniform LDS base (lane*16 implicit)

  // ---- fragment read offsets (swizzled): logical (row, quad) lives at chunk quad^s(row) ----
  int aoff[8], boff[4];
#pragma unroll
  for (int mt = 0; mt < 8; ++mt) {
    const int row = wm * 128 + mt * 16 + c16;
    aoff[mt] = row * 64 + ((quad ^ ((row >> 1) & 3)) * 16);
  }
#pragma unroll
  for (int nt = 0; nt < 4; ++nt) {
    const int col = wn * 64 + nt * 16 + c16;
    boff[nt] = col * 64 + ((quad ^ ((col >> 1) & 3)) * 16);
  }

  f32x4 acc[8][4] = {};

#define STAGE(T)                                          \
  {                                                       \
    const int _ko = (T) * (BK * 2);                       \
    char* _sb = &lds[((T) & 3) * 32768];                  \
    async_ld16(Ag1 + _ko, _sb + wbyte);                   \
    async_ld16(Ag2 + _ko, _sb + 8192 + wbyte);            \
    async_ld16(Bg1 + _ko, _sb + 16384 + wbyte);           \
    async_ld16(Bg2 + _ko, _sb + 24576 + wbyte);           \
  }

  // prologue: 3 tiles in flight (12 loads/wave)
  STAGE(0); STAGE(1); STAGE(2);

#pragma unroll 1
  for (int t = 0; t < NT; ++t) {
    // tile t landed when all but the newest 2 tiles (8 loads) retired; tail drains 8->4->0
    if (t < NT - 2)       asm volatile("s_waitcnt vmcnt(8)" ::: "memory");
    else if (t == NT - 2) asm volatile("s_waitcnt vmcnt(4)" ::: "memory");
    else                  asm volatile("s_waitcnt vmcnt(0)" ::: "memory");
    __builtin_amdgcn_s_barrier();                 // all waves: tile t landed, tile t-1 reads done
    __builtin_amdgcn_sched_barrier(0);

    const char* sb = &lds[(t & 3) * 32768];
    bf16x8 a[8], b[4];
#pragma unroll
    for (int mt = 0; mt < 8; ++mt) a[mt] = *(const bf16x8*)(sb + aoff[mt]);
#pragma unroll
    for (int nt = 0; nt < 4; ++nt) b[nt] = *(const bf16x8*)(sb + 16384 + boff[nt]);

    if (t < NT - 3) STAGE(t + 3);                 // into slot (t-1)&3: freed by this barrier

    asm volatile("s_waitcnt lgkmcnt(0)" ::: "memory");
    __builtin_amdgcn_sched_barrier(0);
    __builtin_amdgcn_s_setprio(1);
#pragma unroll
    for (int mt = 0; mt < 8; ++mt)
#pragma unroll
      for (int nt = 0; nt < 4; ++nt)
        acc[mt][nt] = __builtin_amdgcn_mfma_f32_16x16x32_bf16(a[mt], b[nt], acc[mt][nt], 0, 0, 0);
    __builtin_amdgcn_s_setprio(0);
  }
#undef STAGE

  // Epilogue: C/D layout: col = lane&15, row = quad*4 + reg (verified convention).
  const int colbase = bnBase + wn * 64;
  float c2v[4];
#pragma unroll
  for (int nt = 0; nt < 4; ++nt) c2v[nt] = c2[colbase + nt * 16 + c16];

  const int chunk = bn * 4 + wn;
#pragma unroll
  for (int mt = 0; mt < 8; ++mt) {
#pragma unroll
    for (int r = 0; r < 4; ++r) {
      float sv[4];
#pragma unroll
      for (int nt = 0; nt < 4; ++nt) sv[nt] = 2.0f * acc[mt][nt][r] - c2v[nt];
      float m = sv[0];
      int idx = colbase + c16;
#pragma unroll
      for (int nt = 1; nt < 4; ++nt) {
        if (sv[nt] > m) { m = sv[nt]; idx = colbase + nt * 16 + c16; }
      }
      float l = 0.f;
#pragma unroll
      for (int nt = 0; nt < 4; ++nt) l += __expf(sv[nt] - m);
      for (int d = 1; d < 16; d <<= 1) {
        float om = __shfl_xor(m, d, 64);
        float ol = __shfl_xor(l, d, 64);
        int oi = __shfl_xor(idx, d, 64);
        float M = fmaxf(m, om);
        l = l * __expf(m - M) + ol * __expf(om - M);
        idx = (om > m || (om == m && oi < idx)) ? oi : idx;
        m = M;
      }
      if (c16 == 0) {
        const int row = bmBase + wm * 128 + mt * 16 + quad * 4 + r;
        pm[(size_t)row * NCHUNK + chunk] = m;
        pl[(size_t)row * NCHUNK + chunk] = l;
        pidx[(size_t)row * NCHUNK + chunk] = idx;
      }
    }
  }
}

// ---------- K2: per-row combine — single wave, 2 chunks/lane, no LDS ----------
__global__ __launch_bounds__(64) void combine_kernel(
    const float* __restrict__ pm, const float* __restrict__ pl,
    const int* __restrict__ pidx, const float* __restrict__ x,
    const float* __restrict__ cent, const float* __restrict__ c2,
    const int* __restrict__ y,
    float* __restrict__ loss_part, float* __restrict__ corr_part) {
  const int row = blockIdx.x, t = threadIdx.x;  // t = lane, 0..63
  const int yc = y[row];
  const size_t base = (size_t)row * NCHUNK;

  // two chunks per lane: t (cols t*64..) and t+64 (higher cols)
  const float m0 = pm[base + t],      l0 = pl[base + t];
  const float m1 = pm[base + t + 64], l1 = pl[base + t + 64];
  const int   i0 = pidx[base + t],    i1 = pidx[base + t + 64];
  float m = fmaxf(m0, m1);
  float l = l0 * __expf(m0 - m) + l1 * __expf(m1 - m);
  int idx = (m1 > m0) ? i1 : i0;     // tie keeps lower index (i0 < i1 always)

  // fp32 partial dot: 16 elements per lane (4 float4)
  const float4* xa = (const float4*)(x + (size_t)row * KDIM) + t * 4;
  const float4* ca = (const float4*)(cent + (size_t)yc * KDIM) + t * 4;
  float dot = 0.f;
#pragma unroll
  for (int j = 0; j < 4; ++j) {
    const float4 a = xa[j], b = ca[j];
    dot += a.x * b.x + a.y * b.y + a.z * b.z + a.w * b.w;
  }

  for (int d = 1; d < 64; d <<= 1) {
    const float om = __shfl_xor(m, d, 64);
    const float ol = __shfl_xor(l, d, 64);
    const int oi = __shfl_xor(idx, d, 64);
    const float od = __shfl_xor(dot, d, 64);
    const float M = fmaxf(m, om);
    l = l * __expf(m - M) + ol * __expf(om - M);
    idx = (om > m || (om == m && oi < idx)) ? oi : idx;
    m = M;
    dot += od;
  }
  if (t == 0) {
    const float sy = 2.0f * dot - c2[yc];
    loss_part[row] = __logf(l) + m - sy;
    corr_part[row] = (idx == yc) ? 1.f : 0.f;
  }
}

// ---------- K3: finalize means ----------
__global__ __launch_bounds__(256) void finalize(const float* __restrict__ loss_part,
                                                const float* __restrict__ corr_part,
                                                float* __restrict__ out) {
  const int t = threadIdx.x;
  float s0 = 0.f, s1 = 0.f;
  for (int i = t; i < MDIM; i += 256) { s0 += loss_part[i]; s1 += corr_part[i]; }
  for (int d = 32; d; d >>= 1) {
    s0 += __shfl_down(s0, d, 64);
    s1 += __shfl_down(s1, d, 64);
  }
  __shared__ float r0[4], r1[4];
  if ((t & 63) == 0) { r0[t >> 6] = s0; r1[t >> 6] = s1; }
  __syncthreads();
  if (t == 0) {
    out[0] = (r0[0] + r0[1] + r0[2] + r0[3]) * (1.0f / MDIM);
    out[1] = (r1[0] + r1[1] + r1[2] + r1[3]) * (1.0f / MDIM);
  }
}

// ---------- launch ----------
extern "C" void kernel_launch(void* const* d_in, const int* in_sizes, int n_in,
                              void* d_out, int out_size, void* d_ws, size_t ws_size,
                              hipStream_t stream) {
  const float* x = (const float*)d_in[0];
  const int* y = (const int*)d_in[1];
  const float* cent = (const float*)d_in[2];
  float* out = (float*)d_out;

  char* ws = (char*)d_ws;
  const size_t OFF_XB = 0;                                   // 4 MB
  const size_t OFF_CB = OFF_XB + (size_t)MDIM * KDIM * 2;    // 16 MB
  const size_t OFF_C2 = OFF_CB + (size_t)CDIM * KDIM * 2;    // 32 KB
  const size_t OFF_PM = OFF_C2 + (size_t)CDIM * 4;           // 1 MB
  const size_t OFF_PL = OFF_PM + (size_t)NCHUNK * MDIM * 4;  // 1 MB
  const size_t OFF_PI = OFF_PL + (size_t)NCHUNK * MDIM * 4;  // 1 MB
  const size_t OFF_LP = OFF_PI + (size_t)NCHUNK * MDIM * 4;  // 8 KB
  const size_t OFF_CP = OFF_LP + (size_t)MDIM * 4;           // 8 KB
  const size_t NEED = OFF_CP + (size_t)MDIM * 4;
  if (ws_size < NEED) return;

  unsigned short* xb = (unsigned short*)(ws + OFF_XB);
  unsigned short* cb = (unsigned short*)(ws + OFF_CB);
  float* c2 = (float*)(ws + OFF_C2);
  float* pm = (float*)(ws + OFF_PM);
  float* pl = (float*)(ws + OFF_PL);
  int* pidx = (int*)(ws + OFF_PI);
  float* loss_part = (float*)(ws + OFF_LP);
  float* corr_part = (float*)(ws + OFF_CP);

  convert_all<<<CVT_BLOCKS, 256, 0, stream>>>(x, cent, xb, cb, c2);
  gemm_reduce<<<dim3(CDIM / BN, MDIM / BM), 512, 0, stream>>>(xb, cb, c2, pm, pl, pidx);
  combine_kernel<<<MDIM, 64, 0, stream>>>(pm, pl, pidx, x, cent, c2, y, loss_part, corr_part);
  finalize<<<1, 256, 0, stream>>>(loss_part, corr_part, out);
}